// Round 8
// baseline (490.897 us; speedup 1.0000x reference)
//
#include <hip/hip_runtime.h>

#define N_ROWS 32768
#define DIMS 256
#define K_CODES 1024
#define MT 64      // rows per block (8 waves x 8 rows)
#define NCHUNK 512 // codes per chunk (2 chunks)
#define KC 16      // K per LDS stage
#define SBW 520    // Bs row stride in floats (512 + 8 pad, 16B-aligned)

static constexpr size_t SC_OFF  = 8388608;   // after quantized [32768*256] (float32 elements)
static constexpr size_t IDX_OFF = 8388612;   // after 4 scalars

__device__ inline float wsum64(float v){
  #pragma unroll
  for(int off=32; off; off>>=1) v += __shfl_xor(v, off, 64);
  return v;
}

// ---- row squared norms: bit-exact numpy AVX512 emulation, lane-cooperative -
// np.sum(a*a, -1), n=256: pairwise split 128+128. Per 128-block: 8 AVX512
// accumulators r_j combined lanewise ((r0+r1)+(r2+r3))+((r4+r5)+(r6+r7)),
// then _mm512_reduce_add_ps butterfly (+8)(+4)(+2)(+1). Lane l of a 16-lane
// group holds vector-lane l; the shfl_xor butterfly reproduces the reduce
// order exactly. 16 lanes/row -> 64 B coalesced loads, ~8 VGPRs.
__global__ __launch_bounds__(256) void rowsq_np512_kernel(const float* __restrict__ X,
                                                          const float* __restrict__ CB,
                                                          float* __restrict__ xsq,
                                                          float* __restrict__ csq){
  const int t = threadIdx.x;
  const int wv = t >> 6, l = t & 63;
  const int sub = l >> 4, li = l & 15;      // 4 rows per wave, 16 lanes per row
  #pragma unroll
  for(int p=0; p<4; p++){
    int r = blockIdx.x*64 + p*16 + wv*4 + sub;   // 528 blocks * 64 = 33792 rows
    const float* s0; float* dst;
    if(r < K_CODES){ s0 = CB + (size_t)r*DIMS; dst = csq + r; }
    else { s0 = X + (size_t)(r - K_CODES)*DIMS; dst = xsq + (r - K_CODES); }
    float blk[2];
    #pragma unroll
    for(int bb=0; bb<2; bb++){
      float q[8];
      #pragma unroll
      for(int j=0;j<8;j++){
        float a = s0[bb*128 + j*16 + li];
        q[j] = __fmul_rn(a, a);
      }
      float v = __fadd_rn(__fadd_rn(__fadd_rn(q[0],q[1]), __fadd_rn(q[2],q[3])),
                          __fadd_rn(__fadd_rn(q[4],q[5]), __fadd_rn(q[6],q[7])));
      v = __fadd_rn(v, __shfl_xor(v, 8, 64));
      v = __fadd_rn(v, __shfl_xor(v, 4, 64));
      v = __fadd_rn(v, __shfl_xor(v, 2, 64));
      v = __fadd_rn(v, __shfl_xor(v, 1, 64));
      blk[bb] = v;
    }
    if(li == 0) *dst = __fadd_rn(blk[0], blk[1]);
  }
}

// --------- fused: distances + argmin + softmax + quant gather ---------------
// R8: A off the LDS pipe + full-width B + single-barrier dbuf.
//  * wave-uniform A: ty = t>>6 (wave id), so each wave's 8 rows are uniform.
//    A addresses built from readfirstlane(t>>6) -> scalar/SMEM (or broadcast
//    VMEM) loads, NOT LDS. Per k the LDS pipe now serves only 2 full-width
//    ds_read_b128 of B (64 lanes x 16 B distinct) per 64 FMAs — half of R7.
//  * NCHUNK=512 (tx = t&63 spans 64 code-slots x 8 codes) -> 2 chunks; the
//    argmin/stats butterflies become clean full-wave 6-step reductions.
//  * double-buffered Bs with ONE barrier per stage: FMA reads buf[cur] while
//    the next stage's global prefetch sits in regs; commit to buf[cur^1]
//    after the FMAs; barrier. (R7 had 2 barriers + serialized write->read.)
//  * 512 thr, __launch_bounds__(512,4): 2 blocks/CU, 16 waves/CU (2x R7 TLP);
//    live set ~115 VGPR (acc 64 + B-prefetch 16 + a2 16 + addr) <= 128.
// The per-(row,code) single-accumulator ascending-k fmaf chain is unchanged
// -> distances remain bit-exact vs the CPU BLAS reference.
__global__ __launch_bounds__(512,4) void fused_argmin_kernel(
    const float* __restrict__ X, const float* __restrict__ CB,
    const float* __restrict__ xsq, const float* __restrict__ csq,
    float* __restrict__ hist, float* __restrict__ acc_sc,
    float* __restrict__ out)
{
  __shared__ __align__(16) float Bs[2][KC][SBW];    // 66.6 KB
  __shared__ __align__(16) float4 cstat[2][MT];     // 2 KB: {dl, kl-bits, s1, t2s}
  __shared__ int sk[MT];
  const int t  = threadIdx.x;                 // 0..511
  const int tx = t & 63;                      // code slot within wave
  const int wid = __builtin_amdgcn_readfirstlane(t >> 6);   // wave id 0..7 (uniform)
  const int m0 = blockIdx.x * MT;

  const float* Aw = X + (size_t)(m0 + wid*8)*DIMS;          // uniform base

  float xs_[8];                               // wave-uniform row norms
  #pragma unroll
  for(int i=0;i<8;i++) xs_[i] = xsq[m0 + wid*8 + i];

  // ---- stage-0 prefetch + commit to buf 0 ---------------------------------
  float4 b4p[4];
  {
    const float* Bg = CB + (size_t)t*DIMS;    // chunk 0, code t, k 0..15
    #pragma unroll
    for(int q=0;q<4;q++) b4p[q] = *(const float4*)(Bg + q*4);
  }
  #pragma unroll
  for(int q=0;q<4;q++){
    Bs[0][q*4+0][t]=b4p[q].x; Bs[0][q*4+1][t]=b4p[q].y;
    Bs[0][q*4+2][t]=b4p[q].z; Bs[0][q*4+3][t]=b4p[q].w;
  }
  __syncthreads();

  float acc[8][8];
  #pragma unroll
  for(int i=0;i<8;i++)
    #pragma unroll
    for(int j=0;j<8;j++) acc[i][j]=0.f;

  for(int s=0; s<32; s++){                    // 2 chunks x 16 stages
    const int cur = s & 1;
    // prefetch next stage into regs (latency hides under the FMA phase)
    {
      int s2 = (s+1) & 31;
      const float* Bg = CB + (size_t)((s2>>4)*NCHUNK + t)*DIMS + (s2&15)*KC;
      #pragma unroll
      for(int q=0;q<4;q++) b4p[q] = *(const float4*)(Bg + q*4);
    }
    // K-chain: ascending k, one fmaf chain per (row,code)
    const int kb = (s&15)*KC;
    #pragma unroll
    for(int k2=0;k2<KC/2;k2++){
      float2 a2[8];                           // wave-uniform A pair loads
      #pragma unroll
      for(int r=0;r<8;r++) a2[r] = *(const float2*)(Aw + r*DIMS + kb + k2*2);
      #pragma unroll
      for(int kk=0;kk<2;kk++){
        const int k = k2*2 + kk;
        float4 b0 = *(const float4*)&Bs[cur][k][tx*4];        // codes 0..255
        float4 b1 = *(const float4*)&Bs[cur][k][256 + tx*4];  // codes 256..511
        float b_[8]={b0.x,b0.y,b0.z,b0.w, b1.x,b1.y,b1.z,b1.w};
        #pragma unroll
        for(int r=0;r<8;r++){
          float av = kk ? a2[r].y : a2[r].x;
          #pragma unroll
          for(int j=0;j<8;j++)
            acc[r][j] = fmaf(av, b_[j], acc[r][j]);
        }
      }
    }
    // commit prefetched stage to the other buffer (no read of it until after
    // the barrier; writes overlap other waves' FMA tail)
    #pragma unroll
    for(int q=0;q<4;q++){
      Bs[cur^1][q*4+0][t]=b4p[q].x; Bs[cur^1][q*4+1][t]=b4p[q].y;
      Bs[cur^1][q*4+2][t]=b4p[q].z; Bs[cur^1][q*4+3][t]=b4p[q].w;
    }
    __syncthreads();

    // ---- chunk epilogue every 16 stages ------------------------------------
    if((s & 15) == 15){
      const int nc = s >> 4;
      const int n0c = nc * NCHUNK;
      float csv[8];
      { float4 c0 = *(const float4*)(csq + n0c + tx*4);
        float4 c1 = *(const float4*)(csq + n0c + 256 + tx*4);
        csv[0]=c0.x; csv[1]=c0.y; csv[2]=c0.z; csv[3]=c0.w;
        csv[4]=c1.x; csv[5]=c1.y; csv[6]=c1.z; csv[7]=c1.w; }
      #pragma unroll
      for(int i=0;i<8;i++){
        float xs = xs_[i];
        float d[8];
        #pragma unroll
        for(int j=0;j<8;j++){
          // contraction-safe: 2*acc exact, fl(t - 2*acc)
          float d2 = (xs + csv[j]) - 2.0f*acc[i][j];
          d[j] = sqrtf(fmaxf(d2, 0.f));
        }
        // thread-local argmin, ascending kidx, strict < (first-occurrence tie)
        float dl = INFINITY; int kl = 0;
        #pragma unroll
        for(int j=0;j<8;j++){
          int kidx = n0c + (j>>2)*256 + tx*4 + (j&3);   // ascending in j
          if(d[j] < dl){ dl = d[j]; kl = kidx; }
        }
        // full-wave butterfly (64 lanes share this row)
        #pragma unroll
        for(int off=1; off<64; off<<=1){
          float od = __shfl_xor(dl, off, 64);
          int   ok = __shfl_xor(kl, off, 64);
          if(od < dl || (od == dl && ok < kl)){ dl = od; kl = ok; }
        }
        // chunk softmax stats shifted at chunk min: l = (dl - d)*100 <= 0
        float s1=0.f, t2s=0.f;
        #pragma unroll
        for(int j=0;j<8;j++){
          float l = (dl - d[j])*100.0f;
          float e = expf(l);
          s1 += e; t2s = fmaf(e, l, t2s);
        }
        #pragma unroll
        for(int off=1; off<64; off<<=1){
          s1  += __shfl_xor(s1,  off, 64);
          t2s += __shfl_xor(t2s, off, 64);
        }
        if(tx == 0)
          cstat[nc][wid*8 + i] = make_float4(dl, __int_as_float(kl), s1, t2s);
      }
      #pragma unroll
      for(int i=0;i<8;i++)
        #pragma unroll
        for(int j=0;j<8;j++) acc[i][j]=0.f;
    }
  }

  // ---- final merge: one row per lane of wave 0 (ascending nc = same
  //      first-occurrence semantics as the sequential merge) ----------------
  __syncthreads();
  float plogp = 0.f;
  if(t < MT){
    float4 c0 = cstat[0][t];
    float dm = c0.x; int km = __float_as_int(c0.y);
    float Ss = c0.z; float Ts = c0.w;
    {
      float4 cn = cstat[1][t];
      float dl = cn.x; int kl = __float_as_int(cn.y);
      float s1 = cn.z, t2s = cn.w;
      if(dl < dm){                       // strict <: tie keeps chunk 0 (smaller idx)
        float del = 100.0f*(dl - dm); float al = expf(del);
        Ts = al*(Ts + Ss*del) + t2s;
        Ss = al*Ss + s1;
        dm = dl; km = kl;
      } else {
        float del = 100.0f*(dm - dl); float al = expf(del);
        Ts += al*(t2s + s1*del);
        Ss += al*s1;
      }
    }
    int n = m0 + t;
    out[IDX_OFF + n] = (float)km;
    sk[t] = km;
    atomicAdd(hist + km, 1.0f);
    plogp = Ts/Ss - logf(Ss);
  }
  plogp = wsum64(plogp);
  if((t & 63) == 0) atomicAdd(acc_sc + 1, plogp);   // waves 1-7 add 0

  // ---- fused quant gather + mse -------------------------------------------
  __syncthreads();                 // sk[] visible to all waves
  {
    int lane = t & 63;             // 8 waves x 8 rows
    int row0 = wid*8;
    float mse = 0.f;
    #pragma unroll
    for(int r=0;r<8;r++){
      int n = m0 + row0 + r;
      int k = sk[row0 + r];
      float4 cb4 = *(const float4*)(CB + (size_t)k*DIMS + lane*4);
      float4 x4  = *(const float4*)(X  + (size_t)n*DIMS + lane*4);
      float e0=x4.x-cb4.x, e1=x4.y-cb4.y, e2=x4.z-cb4.z, e3=x4.w-cb4.w;
      mse += e0*e0 + e1*e1 + e2*e2 + e3*e3;
      *reinterpret_cast<float4*>(out + (size_t)n*DIMS + lane*4) = cb4;
    }
    mse = wsum64(mse);
    if(lane==0) atomicAdd(acc_sc+0, mse);
  }
}

// ---------------- finalize scalars (float32) --------------------------------
__global__ __launch_bounds__(256) void finalize_kernel(const float* __restrict__ hist,
                                                       const float* __restrict__ acc_sc,
                                                       float* __restrict__ out){
  __shared__ float red[256];
  int t = threadIdx.x;
  float s = 0.f;
  #pragma unroll
  for(int c=0;c<4;c++){
    float ap = hist[c*256 + t] * (1.0f/32768.0f);   // avg_probs ~ argmin histogram
    s += ap * logf(ap + 1e-5f);
  }
  red[t] = s; __syncthreads();
  for(int off=128; off; off>>=1){
    if(t<off) red[t]+=red[t+off];
    __syncthreads();
  }
  if(t==0){
    float avg_entropy    = -red[0];
    float mse            = acc_sc[0] * (1.0f/8388608.0f);
    float sample_entropy = -(acc_sc[1] * (1.0f/32768.0f));
    float commit = 0.5f*mse*0.25f;
    float cbl    = 0.5f*mse;
    float ent    = (sample_entropy - avg_entropy)*0.1f;
    float vq     = cbl + commit + ent;
    out[SC_OFF+0] = vq;
    out[SC_OFF+1] = commit;
    out[SC_OFF+2] = cbl;
    out[SC_OFF+3] = ent;
  }
}

extern "C" void kernel_launch(void* const* d_in, const int* in_sizes, int n_in,
                              void* d_out, int out_size, void* d_ws, size_t ws_size,
                              hipStream_t stream){
  const float* X  = (const float*)d_in[0];
  const float* CB = (const float*)d_in[1];
  float* out = (float*)d_out;                        // float32 output buffer
  float* xsq     = (float*)d_ws;                     // [32768]
  float* csq     = xsq + N_ROWS;                     // [1024]
  float* hist    = csq + K_CODES;                    // [1024]
  float* acc_sc  = hist + K_CODES;                   // [2]: mse, plogp

  hipMemsetAsync(hist, 0, (K_CODES+2)*sizeof(float), stream);
  rowsq_np512_kernel <<<(K_CODES+N_ROWS)/64, 256, 0, stream>>>(X, CB, xsq, csq);
  fused_argmin_kernel<<<N_ROWS/MT, 512, 0, stream>>>(X, CB, xsq, csq, hist, acc_sc, out);
  finalize_kernel    <<<1, 256, 0, stream>>>(hist, acc_sc, out);
}

// Round 9
// 487.874 us; speedup vs baseline: 1.0062x; 1.0062x over previous
//
#include <hip/hip_runtime.h>

#define N_ROWS 32768
#define DIMS 256
#define K_CODES 1024
#define MT 64      // rows per block (8 waves x 8 rows)
#define NCHUNK 512 // codes per chunk (2 chunks)
#define KC 16      // K per LDS stage
#define SBW 520    // Bs row stride in floats (512 + 8 pad, 16B-aligned)

static constexpr size_t SC_OFF  = 8388608;   // after quantized [32768*256] (float32 elements)
static constexpr size_t IDX_OFF = 8388612;   // after 4 scalars

__device__ inline float wsum64(float v){
  #pragma unroll
  for(int off=32; off; off>>=1) v += __shfl_xor(v, off, 64);
  return v;
}

// ---- row squared norms: bit-exact numpy AVX512 emulation, lane-cooperative -
// np.sum(a*a, -1), n=256: pairwise split 128+128. Per 128-block: 8 AVX512
// accumulators r_j combined lanewise ((r0+r1)+(r2+r3))+((r4+r5)+(r6+r7)),
// then _mm512_reduce_add_ps butterfly (+8)(+4)(+2)(+1). Lane l of a 16-lane
// group holds vector-lane l; the shfl_xor butterfly reproduces the reduce
// order exactly. 16 lanes/row -> 64 B coalesced loads, ~8 VGPRs.
__global__ __launch_bounds__(256) void rowsq_np512_kernel(const float* __restrict__ X,
                                                          const float* __restrict__ CB,
                                                          float* __restrict__ xsq,
                                                          float* __restrict__ csq){
  const int t = threadIdx.x;
  const int wv = t >> 6, l = t & 63;
  const int sub = l >> 4, li = l & 15;      // 4 rows per wave, 16 lanes per row
  #pragma unroll
  for(int p=0; p<4; p++){
    int r = blockIdx.x*64 + p*16 + wv*4 + sub;   // 528 blocks * 64 = 33792 rows
    const float* s0; float* dst;
    if(r < K_CODES){ s0 = CB + (size_t)r*DIMS; dst = csq + r; }
    else { s0 = X + (size_t)(r - K_CODES)*DIMS; dst = xsq + (r - K_CODES); }
    float blk[2];
    #pragma unroll
    for(int bb=0; bb<2; bb++){
      float q[8];
      #pragma unroll
      for(int j=0;j<8;j++){
        float a = s0[bb*128 + j*16 + li];
        q[j] = __fmul_rn(a, a);
      }
      float v = __fadd_rn(__fadd_rn(__fadd_rn(q[0],q[1]), __fadd_rn(q[2],q[3])),
                          __fadd_rn(__fadd_rn(q[4],q[5]), __fadd_rn(q[6],q[7])));
      v = __fadd_rn(v, __shfl_xor(v, 8, 64));
      v = __fadd_rn(v, __shfl_xor(v, 4, 64));
      v = __fadd_rn(v, __shfl_xor(v, 2, 64));
      v = __fadd_rn(v, __shfl_xor(v, 1, 64));
      blk[bb] = v;
    }
    if(li == 0) *dst = __fadd_rn(blk[0], blk[1]);
  }
}

// --------- fused: distances + argmin + softmax + quant gather ---------------
// R9: R8's structure with the occupancy target PINNED.
//  * R8 regression root-cause: __launch_bounds__(512,4) only sets a MIN;
//    the allocator targeted 8 waves/EU (64-VGPR budget) though LDS caps the
//    kernel at 2 blocks/CU = 4 waves/EU -> acc[8][8] spilled (VGPR=64,
//    +25 MB scratch, +150us of copy VALU). amdgpu_waves_per_eu(4,4) forces
//    the 128-VGPR budget that the ~110-reg live set actually needs.
//  * wave-uniform A via readfirstlane wave id -> scalar loads, off the LDS
//    pipe; per k the LDS serves only 2 full-width ds_read_b128 per 64 FMAs.
//  * NCHUNK=512, 2 chunks; full-wave butterflies; dbuf Bs, 1 barrier/stage.
// The per-(row,code) single-accumulator ascending-k fmaf chain is unchanged
// -> distances remain bit-exact vs the CPU BLAS reference.
__global__ __launch_bounds__(512)
__attribute__((amdgpu_waves_per_eu(4,4)))
void fused_argmin_kernel(
    const float* __restrict__ X, const float* __restrict__ CB,
    const float* __restrict__ xsq, const float* __restrict__ csq,
    float* __restrict__ hist, float* __restrict__ acc_sc,
    float* __restrict__ out)
{
  __shared__ __align__(16) float Bs[2][KC][SBW];    // 66.6 KB
  __shared__ __align__(16) float4 cstat[2][MT];     // 2 KB: {dl, kl-bits, s1, t2s}
  __shared__ int sk[MT];
  const int t  = threadIdx.x;                 // 0..511
  const int tx = t & 63;                      // code slot within wave
  const int wid = __builtin_amdgcn_readfirstlane(t >> 6);   // wave id 0..7 (uniform)
  const int m0 = blockIdx.x * MT;

  const float* Aw = X + (size_t)(m0 + wid*8)*DIMS;          // uniform base

  float xs_[8];                               // wave-uniform row norms
  #pragma unroll
  for(int i=0;i<8;i++) xs_[i] = xsq[m0 + wid*8 + i];

  // ---- stage-0 prefetch + commit to buf 0 ---------------------------------
  float4 b4p[4];
  {
    const float* Bg = CB + (size_t)t*DIMS;    // chunk 0, code t, k 0..15
    #pragma unroll
    for(int q=0;q<4;q++) b4p[q] = *(const float4*)(Bg + q*4);
  }
  #pragma unroll
  for(int q=0;q<4;q++){
    Bs[0][q*4+0][t]=b4p[q].x; Bs[0][q*4+1][t]=b4p[q].y;
    Bs[0][q*4+2][t]=b4p[q].z; Bs[0][q*4+3][t]=b4p[q].w;
  }
  __syncthreads();

  float acc[8][8];
  #pragma unroll
  for(int i=0;i<8;i++)
    #pragma unroll
    for(int j=0;j<8;j++) acc[i][j]=0.f;

  for(int s=0; s<32; s++){                    // 2 chunks x 16 stages
    const int cur = s & 1;
    // prefetch next stage into regs (latency hides under the FMA phase)
    {
      int s2 = (s+1) & 31;
      const float* Bg = CB + (size_t)((s2>>4)*NCHUNK + t)*DIMS + (s2&15)*KC;
      #pragma unroll
      for(int q=0;q<4;q++) b4p[q] = *(const float4*)(Bg + q*4);
    }
    // K-chain: ascending k, one fmaf chain per (row,code)
    const int kb = (s&15)*KC;
    #pragma unroll
    for(int k2=0;k2<KC/2;k2++){
      float2 a2[8];                           // wave-uniform A pair loads
      #pragma unroll
      for(int r=0;r<8;r++) a2[r] = *(const float2*)(Aw + r*DIMS + kb + k2*2);
      #pragma unroll
      for(int kk=0;kk<2;kk++){
        const int k = k2*2 + kk;
        float4 b0 = *(const float4*)&Bs[cur][k][tx*4];        // codes 0..255
        float4 b1 = *(const float4*)&Bs[cur][k][256 + tx*4];  // codes 256..511
        float b_[8]={b0.x,b0.y,b0.z,b0.w, b1.x,b1.y,b1.z,b1.w};
        #pragma unroll
        for(int r=0;r<8;r++){
          float av = kk ? a2[r].y : a2[r].x;
          #pragma unroll
          for(int j=0;j<8;j++)
            acc[r][j] = fmaf(av, b_[j], acc[r][j]);
        }
      }
    }
    // commit prefetched stage to the other buffer (no read of it until after
    // the barrier; writes overlap other waves' FMA tail)
    #pragma unroll
    for(int q=0;q<4;q++){
      Bs[cur^1][q*4+0][t]=b4p[q].x; Bs[cur^1][q*4+1][t]=b4p[q].y;
      Bs[cur^1][q*4+2][t]=b4p[q].z; Bs[cur^1][q*4+3][t]=b4p[q].w;
    }
    __syncthreads();

    // ---- chunk epilogue every 16 stages ------------------------------------
    if((s & 15) == 15){
      const int nc = s >> 4;
      const int n0c = nc * NCHUNK;
      float csv[8];
      { float4 c0 = *(const float4*)(csq + n0c + tx*4);
        float4 c1 = *(const float4*)(csq + n0c + 256 + tx*4);
        csv[0]=c0.x; csv[1]=c0.y; csv[2]=c0.z; csv[3]=c0.w;
        csv[4]=c1.x; csv[5]=c1.y; csv[6]=c1.z; csv[7]=c1.w; }
      #pragma unroll
      for(int i=0;i<8;i++){
        float xs = xs_[i];
        float d[8];
        #pragma unroll
        for(int j=0;j<8;j++){
          // contraction-safe: 2*acc exact, fl(t - 2*acc)
          float d2 = (xs + csv[j]) - 2.0f*acc[i][j];
          d[j] = sqrtf(fmaxf(d2, 0.f));
        }
        // thread-local argmin, ascending kidx, strict < (first-occurrence tie)
        float dl = INFINITY; int kl = 0;
        #pragma unroll
        for(int j=0;j<8;j++){
          int kidx = n0c + (j>>2)*256 + tx*4 + (j&3);   // ascending in j
          if(d[j] < dl){ dl = d[j]; kl = kidx; }
        }
        // full-wave butterfly (64 lanes share this row)
        #pragma unroll
        for(int off=1; off<64; off<<=1){
          float od = __shfl_xor(dl, off, 64);
          int   ok = __shfl_xor(kl, off, 64);
          if(od < dl || (od == dl && ok < kl)){ dl = od; kl = ok; }
        }
        // chunk softmax stats shifted at chunk min: l = (dl - d)*100 <= 0
        float s1=0.f, t2s=0.f;
        #pragma unroll
        for(int j=0;j<8;j++){
          float l = (dl - d[j])*100.0f;
          float e = expf(l);
          s1 += e; t2s = fmaf(e, l, t2s);
        }
        #pragma unroll
        for(int off=1; off<64; off<<=1){
          s1  += __shfl_xor(s1,  off, 64);
          t2s += __shfl_xor(t2s, off, 64);
        }
        if(tx == 0)
          cstat[nc][wid*8 + i] = make_float4(dl, __int_as_float(kl), s1, t2s);
      }
      #pragma unroll
      for(int i=0;i<8;i++)
        #pragma unroll
        for(int j=0;j<8;j++) acc[i][j]=0.f;
    }
  }

  // ---- final merge: one row per lane of wave 0 (ascending nc = same
  //      first-occurrence semantics as the sequential merge) ----------------
  __syncthreads();
  float plogp = 0.f;
  if(t < MT){
    float4 c0 = cstat[0][t];
    float dm = c0.x; int km = __float_as_int(c0.y);
    float Ss = c0.z; float Ts = c0.w;
    {
      float4 cn = cstat[1][t];
      float dl = cn.x; int kl = __float_as_int(cn.y);
      float s1 = cn.z, t2s = cn.w;
      if(dl < dm){                       // strict <: tie keeps chunk 0 (smaller idx)
        float del = 100.0f*(dl - dm); float al = expf(del);
        Ts = al*(Ts + Ss*del) + t2s;
        Ss = al*Ss + s1;
        dm = dl; km = kl;
      } else {
        float del = 100.0f*(dm - dl); float al = expf(del);
        Ts += al*(t2s + s1*del);
        Ss += al*s1;
      }
    }
    int n = m0 + t;
    out[IDX_OFF + n] = (float)km;
    sk[t] = km;
    atomicAdd(hist + km, 1.0f);
    plogp = Ts/Ss - logf(Ss);
  }
  plogp = wsum64(plogp);
  if((t & 63) == 0) atomicAdd(acc_sc + 1, plogp);   // waves 1-7 add 0

  // ---- fused quant gather + mse -------------------------------------------
  __syncthreads();                 // sk[] visible to all waves
  {
    int lane = t & 63;             // 8 waves x 8 rows
    int row0 = wid*8;
    float mse = 0.f;
    #pragma unroll
    for(int r=0;r<8;r++){
      int n = m0 + row0 + r;
      int k = sk[row0 + r];
      float4 cb4 = *(const float4*)(CB + (size_t)k*DIMS + lane*4);
      float4 x4  = *(const float4*)(X  + (size_t)n*DIMS + lane*4);
      float e0=x4.x-cb4.x, e1=x4.y-cb4.y, e2=x4.z-cb4.z, e3=x4.w-cb4.w;
      mse += e0*e0 + e1*e1 + e2*e2 + e3*e3;
      *reinterpret_cast<float4*>(out + (size_t)n*DIMS + lane*4) = cb4;
    }
    mse = wsum64(mse);
    if(lane==0) atomicAdd(acc_sc+0, mse);
  }
}

// ---------------- finalize scalars (float32) --------------------------------
__global__ __launch_bounds__(256) void finalize_kernel(const float* __restrict__ hist,
                                                       const float* __restrict__ acc_sc,
                                                       float* __restrict__ out){
  __shared__ float red[256];
  int t = threadIdx.x;
  float s = 0.f;
  #pragma unroll
  for(int c=0;c<4;c++){
    float ap = hist[c*256 + t] * (1.0f/32768.0f);   // avg_probs ~ argmin histogram
    s += ap * logf(ap + 1e-5f);
  }
  red[t] = s; __syncthreads();
  for(int off=128; off; off>>=1){
    if(t<off) red[t]+=red[t+off];
    __syncthreads();
  }
  if(t==0){
    float avg_entropy    = -red[0];
    float mse            = acc_sc[0] * (1.0f/8388608.0f);
    float sample_entropy = -(acc_sc[1] * (1.0f/32768.0f));
    float commit = 0.5f*mse*0.25f;
    float cbl    = 0.5f*mse;
    float ent    = (sample_entropy - avg_entropy)*0.1f;
    float vq     = cbl + commit + ent;
    out[SC_OFF+0] = vq;
    out[SC_OFF+1] = commit;
    out[SC_OFF+2] = cbl;
    out[SC_OFF+3] = ent;
  }
}

extern "C" void kernel_launch(void* const* d_in, const int* in_sizes, int n_in,
                              void* d_out, int out_size, void* d_ws, size_t ws_size,
                              hipStream_t stream){
  const float* X  = (const float*)d_in[0];
  const float* CB = (const float*)d_in[1];
  float* out = (float*)d_out;                        // float32 output buffer
  float* xsq     = (float*)d_ws;                     // [32768]
  float* csq     = xsq + N_ROWS;                     // [1024]
  float* hist    = csq + K_CODES;                    // [1024]
  float* acc_sc  = hist + K_CODES;                   // [2]: mse, plogp

  hipMemsetAsync(hist, 0, (K_CODES+2)*sizeof(float), stream);
  rowsq_np512_kernel <<<(K_CODES+N_ROWS)/64, 256, 0, stream>>>(X, CB, xsq, csq);
  fused_argmin_kernel<<<N_ROWS/MT, 512, 0, stream>>>(X, CB, xsq, csq, hist, acc_sc, out);
  finalize_kernel    <<<1, 256, 0, stream>>>(hist, acc_sc, out);
}

// Round 10
// 417.291 us; speedup vs baseline: 1.1764x; 1.1691x over previous
//
#include <hip/hip_runtime.h>

#define N_ROWS 32768
#define DIMS 256
#define K_CODES 1024
#define MT 32      // rows per block (4 waves x 8 rows)
#define NCHUNK 512 // codes per chunk (2 chunks)
#define KC 8       // K per LDS stage (16 staging regs/thread)
#define SBW 520    // Bs row stride in floats (512 + 8 pad)

static constexpr size_t SC_OFF  = 8388608;   // after quantized [32768*256] (float32 elements)
static constexpr size_t IDX_OFF = 8388612;   // after 4 scalars

__device__ inline float wsum64(float v){
  #pragma unroll
  for(int off=32; off; off>>=1) v += __shfl_xor(v, off, 64);
  return v;
}

// ---- row squared norms: bit-exact numpy AVX512 emulation, lane-cooperative -
// np.sum(a*a, -1), n=256: pairwise split 128+128. Per 128-block: 8 AVX512
// accumulators r_j combined lanewise ((r0+r1)+(r2+r3))+((r4+r5)+(r6+r7)),
// then _mm512_reduce_add_ps butterfly (+8)(+4)(+2)(+1). Lane l of a 16-lane
// group holds vector-lane l; the shfl_xor butterfly reproduces the reduce
// order exactly. 16 lanes/row -> 64 B coalesced loads, ~8 VGPRs.
__global__ __launch_bounds__(256) void rowsq_np512_kernel(const float* __restrict__ X,
                                                          const float* __restrict__ CB,
                                                          float* __restrict__ xsq,
                                                          float* __restrict__ csq){
  const int t = threadIdx.x;
  const int wv = t >> 6, l = t & 63;
  const int sub = l >> 4, li = l & 15;      // 4 rows per wave, 16 lanes per row
  #pragma unroll
  for(int p=0; p<4; p++){
    int r = blockIdx.x*64 + p*16 + wv*4 + sub;   // 528 blocks * 64 = 33792 rows
    const float* s0; float* dst;
    if(r < K_CODES){ s0 = CB + (size_t)r*DIMS; dst = csq + r; }
    else { s0 = X + (size_t)(r - K_CODES)*DIMS; dst = xsq + (r - K_CODES); }
    float blk[2];
    #pragma unroll
    for(int bb=0; bb<2; bb++){
      float q[8];
      #pragma unroll
      for(int j=0;j<8;j++){
        float a = s0[bb*128 + j*16 + li];
        q[j] = __fmul_rn(a, a);
      }
      float v = __fadd_rn(__fadd_rn(__fadd_rn(q[0],q[1]), __fadd_rn(q[2],q[3])),
                          __fadd_rn(__fadd_rn(q[4],q[5]), __fadd_rn(q[6],q[7])));
      v = __fadd_rn(v, __shfl_xor(v, 8, 64));
      v = __fadd_rn(v, __shfl_xor(v, 4, 64));
      v = __fadd_rn(v, __shfl_xor(v, 2, 64));
      v = __fadd_rn(v, __shfl_xor(v, 1, 64));
      blk[bb] = v;
    }
    if(li == 0) *dst = __fadd_rn(blk[0], blk[1]);
  }
}

// --------- fused: distances + argmin + softmax + quant gather ---------------
// R10: R8's structure executed at 256 threads where the allocator behaves.
//  * R8/R9 root-cause: at 512 thr/block the compiler pins VGPR=64 (attributes
//    ignored) -> acc[8][8] can never fit -> AGPR/scratch shuffle (+150us).
//    At 256 thr R7 proved VGPR=112 spill-free. This port keeps everything
//    else: wave-uniform A (readfirstlane wave id -> scalar loads, off the
//    LDS pipe), full-width B (2 ds_read_b128 per 64 FMAs), dbuf Bs with one
//    barrier per stage.
//  * 4 waves x 8 rows (MT=32), NCHUNK=512, KC=8: staging = 4 float4 = 16
//    regs (codes t, t+256). Live set ~90 <= 128. LDS 34.5 KB -> grid 1024 =
//    exactly 4 blocks/CU co-resident, 4 waves/SIMD TLP.
// The per-(row,code) single-accumulator ascending-k fmaf chain is unchanged
// -> distances remain bit-exact vs the CPU BLAS reference.
__global__ __launch_bounds__(256,2) void fused_argmin_kernel(
    const float* __restrict__ X, const float* __restrict__ CB,
    const float* __restrict__ xsq, const float* __restrict__ csq,
    float* __restrict__ hist, float* __restrict__ acc_sc,
    float* __restrict__ out)
{
  __shared__ __align__(16) float Bs[2][KC][SBW];    // 33.3 KB
  __shared__ __align__(16) float4 cstat[2][MT];     // 1 KB: {dl, kl-bits, s1, t2s}
  __shared__ int sk[MT];
  const int t  = threadIdx.x;                 // 0..255
  const int tx = t & 63;                      // code slot within wave
  const int wid = __builtin_amdgcn_readfirstlane(t >> 6);   // wave id 0..3 (uniform)
  const int m0 = blockIdx.x * MT;

  const float* Aw = X + (size_t)(m0 + wid*8)*DIMS;          // uniform base

  float xs_[8];                               // wave-uniform row norms
  #pragma unroll
  for(int i=0;i<8;i++) xs_[i] = xsq[m0 + wid*8 + i];

  // ---- stage-0 prefetch + commit to buf 0 ---------------------------------
  float4 b4p[4];                              // codes t and t+256, k 0..7
  {
    const float* Bg  = CB + (size_t)t*DIMS;
    const float* Bg2 = CB + (size_t)(256 + t)*DIMS;
    b4p[0] = *(const float4*)(Bg);  b4p[1] = *(const float4*)(Bg + 4);
    b4p[2] = *(const float4*)(Bg2); b4p[3] = *(const float4*)(Bg2 + 4);
  }
  #pragma unroll
  for(int q=0;q<2;q++)
    #pragma unroll
    for(int j=0;j<4;j++){
      Bs[0][q*4+j][t]       = ((const float*)&b4p[q])[j];
      Bs[0][q*4+j][256 + t] = ((const float*)&b4p[2+q])[j];
    }
  __syncthreads();

  float acc[8][8];
  #pragma unroll
  for(int i=0;i<8;i++)
    #pragma unroll
    for(int j=0;j<8;j++) acc[i][j]=0.f;

  for(int s=0; s<64; s++){                    // 2 chunks x 32 stages
    const int cur = s & 1;
    // prefetch next stage into regs (latency hides under the FMA phase)
    {
      int s2 = (s+1) & 63;
      const float* Bg  = CB + (size_t)((s2>>5)*NCHUNK + t)*DIMS + (s2&31)*KC;
      const float* Bg2 = Bg + 256*DIMS;
      b4p[0] = *(const float4*)(Bg);  b4p[1] = *(const float4*)(Bg + 4);
      b4p[2] = *(const float4*)(Bg2); b4p[3] = *(const float4*)(Bg2 + 4);
    }
    // K-chain: ascending k, one fmaf chain per (row,code); A via uniform
    // scalar loads (never touches LDS)
    const int kb = (s&31)*KC;
    #pragma unroll
    for(int k2=0;k2<KC/2;k2++){
      float2 a2[8];
      #pragma unroll
      for(int r=0;r<8;r++) a2[r] = *(const float2*)(Aw + r*DIMS + kb + k2*2);
      #pragma unroll
      for(int kk=0;kk<2;kk++){
        const int k = k2*2 + kk;
        float4 b0 = *(const float4*)&Bs[cur][k][tx*4];        // codes 0..255
        float4 b1 = *(const float4*)&Bs[cur][k][256 + tx*4];  // codes 256..511
        float b_[8]={b0.x,b0.y,b0.z,b0.w, b1.x,b1.y,b1.z,b1.w};
        #pragma unroll
        for(int r=0;r<8;r++){
          float av = kk ? a2[r].y : a2[r].x;
          #pragma unroll
          for(int j=0;j<8;j++)
            acc[r][j] = fmaf(av, b_[j], acc[r][j]);
        }
      }
    }
    // commit prefetched stage to the other buffer
    #pragma unroll
    for(int q=0;q<2;q++)
      #pragma unroll
      for(int j=0;j<4;j++){
        Bs[cur^1][q*4+j][t]       = ((const float*)&b4p[q])[j];
        Bs[cur^1][q*4+j][256 + t] = ((const float*)&b4p[2+q])[j];
      }
    __syncthreads();

    // ---- chunk epilogue every 32 stages ------------------------------------
    if((s & 31) == 31){
      const int nc = s >> 5;
      const int n0c = nc * NCHUNK;
      float csv[8];
      { float4 c0 = *(const float4*)(csq + n0c + tx*4);
        float4 c1 = *(const float4*)(csq + n0c + 256 + tx*4);
        csv[0]=c0.x; csv[1]=c0.y; csv[2]=c0.z; csv[3]=c0.w;
        csv[4]=c1.x; csv[5]=c1.y; csv[6]=c1.z; csv[7]=c1.w; }
      #pragma unroll
      for(int i=0;i<8;i++){
        float xs = xs_[i];
        float d[8];
        #pragma unroll
        for(int j=0;j<8;j++){
          // contraction-safe: 2*acc exact, fl(t - 2*acc)
          float d2 = (xs + csv[j]) - 2.0f*acc[i][j];
          d[j] = sqrtf(fmaxf(d2, 0.f));
        }
        // thread-local argmin, ascending kidx, strict < (first-occurrence tie)
        float dl = INFINITY; int kl = 0;
        #pragma unroll
        for(int j=0;j<8;j++){
          int kidx = n0c + (j>>2)*256 + tx*4 + (j&3);   // ascending in j
          if(d[j] < dl){ dl = d[j]; kl = kidx; }
        }
        // full-wave butterfly (64 lanes share this row)
        #pragma unroll
        for(int off=1; off<64; off<<=1){
          float od = __shfl_xor(dl, off, 64);
          int   ok = __shfl_xor(kl, off, 64);
          if(od < dl || (od == dl && ok < kl)){ dl = od; kl = ok; }
        }
        // chunk softmax stats shifted at chunk min: l = (dl - d)*100 <= 0
        float s1=0.f, t2s=0.f;
        #pragma unroll
        for(int j=0;j<8;j++){
          float l = (dl - d[j])*100.0f;
          float e = expf(l);
          s1 += e; t2s = fmaf(e, l, t2s);
        }
        #pragma unroll
        for(int off=1; off<64; off<<=1){
          s1  += __shfl_xor(s1,  off, 64);
          t2s += __shfl_xor(t2s, off, 64);
        }
        if(tx == 0)
          cstat[nc][wid*8 + i] = make_float4(dl, __int_as_float(kl), s1, t2s);
      }
      #pragma unroll
      for(int i=0;i<8;i++)
        #pragma unroll
        for(int j=0;j<8;j++) acc[i][j]=0.f;
    }
  }

  // ---- final merge: one row per lane of wave 0 (ascending nc = same
  //      first-occurrence semantics as the sequential merge) ----------------
  __syncthreads();
  float plogp = 0.f;
  if(t < MT){
    float4 c0 = cstat[0][t];
    float dm = c0.x; int km = __float_as_int(c0.y);
    float Ss = c0.z; float Ts = c0.w;
    {
      float4 cn = cstat[1][t];
      float dl = cn.x; int kl = __float_as_int(cn.y);
      float s1 = cn.z, t2s = cn.w;
      if(dl < dm){                       // strict <: tie keeps chunk 0 (smaller idx)
        float del = 100.0f*(dl - dm); float al = expf(del);
        Ts = al*(Ts + Ss*del) + t2s;
        Ss = al*Ss + s1;
        dm = dl; km = kl;
      } else {
        float del = 100.0f*(dm - dl); float al = expf(del);
        Ts += al*(t2s + s1*del);
        Ss += al*s1;
      }
    }
    int n = m0 + t;
    out[IDX_OFF + n] = (float)km;
    sk[t] = km;
    atomicAdd(hist + km, 1.0f);
    plogp = Ts/Ss - logf(Ss);
  }
  plogp = wsum64(plogp);
  if((t & 63) == 0) atomicAdd(acc_sc + 1, plogp);   // waves 1-3 add 0

  // ---- fused quant gather + mse -------------------------------------------
  __syncthreads();                 // sk[] visible to all waves
  {
    int lane = t & 63;             // 4 waves x 8 rows
    int row0 = wid*8;
    float mse = 0.f;
    #pragma unroll
    for(int r=0;r<8;r++){
      int n = m0 + row0 + r;
      int k = sk[row0 + r];
      float4 cb4 = *(const float4*)(CB + (size_t)k*DIMS + lane*4);
      float4 x4  = *(const float4*)(X  + (size_t)n*DIMS + lane*4);
      float e0=x4.x-cb4.x, e1=x4.y-cb4.y, e2=x4.z-cb4.z, e3=x4.w-cb4.w;
      mse += e0*e0 + e1*e1 + e2*e2 + e3*e3;
      *reinterpret_cast<float4*>(out + (size_t)n*DIMS + lane*4) = cb4;
    }
    mse = wsum64(mse);
    if(lane==0) atomicAdd(acc_sc+0, mse);
  }
}

// ---------------- finalize scalars (float32) --------------------------------
__global__ __launch_bounds__(256) void finalize_kernel(const float* __restrict__ hist,
                                                       const float* __restrict__ acc_sc,
                                                       float* __restrict__ out){
  __shared__ float red[256];
  int t = threadIdx.x;
  float s = 0.f;
  #pragma unroll
  for(int c=0;c<4;c++){
    float ap = hist[c*256 + t] * (1.0f/32768.0f);   // avg_probs ~ argmin histogram
    s += ap * logf(ap + 1e-5f);
  }
  red[t] = s; __syncthreads();
  for(int off=128; off; off>>=1){
    if(t<off) red[t]+=red[t+off];
    __syncthreads();
  }
  if(t==0){
    float avg_entropy    = -red[0];
    float mse            = acc_sc[0] * (1.0f/8388608.0f);
    float sample_entropy = -(acc_sc[1] * (1.0f/32768.0f));
    float commit = 0.5f*mse*0.25f;
    float cbl    = 0.5f*mse;
    float ent    = (sample_entropy - avg_entropy)*0.1f;
    float vq     = cbl + commit + ent;
    out[SC_OFF+0] = vq;
    out[SC_OFF+1] = commit;
    out[SC_OFF+2] = cbl;
    out[SC_OFF+3] = ent;
  }
}

extern "C" void kernel_launch(void* const* d_in, const int* in_sizes, int n_in,
                              void* d_out, int out_size, void* d_ws, size_t ws_size,
                              hipStream_t stream){
  const float* X  = (const float*)d_in[0];
  const float* CB = (const float*)d_in[1];
  float* out = (float*)d_out;                        // float32 output buffer
  float* xsq     = (float*)d_ws;                     // [32768]
  float* csq     = xsq + N_ROWS;                     // [1024]
  float* hist    = csq + K_CODES;                    // [1024]
  float* acc_sc  = hist + K_CODES;                   // [2]: mse, plogp

  hipMemsetAsync(hist, 0, (K_CODES+2)*sizeof(float), stream);
  rowsq_np512_kernel <<<(K_CODES+N_ROWS)/64, 256, 0, stream>>>(X, CB, xsq, csq);
  fused_argmin_kernel<<<N_ROWS/MT, 256, 0, stream>>>(X, CB, xsq, csq, hist, acc_sc, out);
  finalize_kernel    <<<1, 256, 0, stream>>>(hist, acc_sc, out);
}

// Round 12
// 402.510 us; speedup vs baseline: 1.2196x; 1.0367x over previous
//
#include <hip/hip_runtime.h>

#define N_ROWS 32768
#define DIMS 256
#define K_CODES 1024
#define MT 32      // rows per block (4 waves x 8 rows)
#define NCHUNK 512 // codes per chunk (2 chunks)
#define KC 8       // K per LDS stage (16 staging regs/thread)
#define SBW 520    // Bs row stride in floats (512 + 8 pad)

static constexpr size_t SC_OFF  = 8388608;   // after quantized [32768*256] (float32 elements)
static constexpr size_t IDX_OFF = 8388612;   // after 4 scalars

__device__ inline float wsum64(float v){
  #pragma unroll
  for(int off=32; off; off>>=1) v += __shfl_xor(v, off, 64);
  return v;
}

__device__ __forceinline__ float bcast_lane(float v, int lane){
  return __int_as_float(__builtin_amdgcn_readlane(__float_as_int(v), lane));
}

// ---- row squared norms: bit-exact numpy AVX512 emulation, lane-cooperative -
// np.sum(a*a, -1), n=256: pairwise split 128+128. Per 128-block: 8 AVX512
// accumulators r_j combined lanewise ((r0+r1)+(r2+r3))+((r4+r5)+(r6+r7)),
// then _mm512_reduce_add_ps butterfly (+8)(+4)(+2)(+1). Lane l of a 16-lane
// group holds vector-lane l; the shfl_xor butterfly reproduces the reduce
// order exactly. 16 lanes/row -> 64 B coalesced loads, ~8 VGPRs.
__global__ __launch_bounds__(256) void rowsq_np512_kernel(const float* __restrict__ X,
                                                          const float* __restrict__ CB,
                                                          float* __restrict__ xsq,
                                                          float* __restrict__ csq){
  const int t = threadIdx.x;
  const int wv = t >> 6, l = t & 63;
  const int sub = l >> 4, li = l & 15;      // 4 rows per wave, 16 lanes per row
  #pragma unroll
  for(int p=0; p<4; p++){
    int r = blockIdx.x*64 + p*16 + wv*4 + sub;   // 528 blocks * 64 = 33792 rows
    const float* s0; float* dst;
    if(r < K_CODES){ s0 = CB + (size_t)r*DIMS; dst = csq + r; }
    else { s0 = X + (size_t)(r - K_CODES)*DIMS; dst = xsq + (r - K_CODES); }
    float blk[2];
    #pragma unroll
    for(int bb=0; bb<2; bb++){
      float q[8];
      #pragma unroll
      for(int j=0;j<8;j++){
        float a = s0[bb*128 + j*16 + li];
        q[j] = __fmul_rn(a, a);
      }
      float v = __fadd_rn(__fadd_rn(__fadd_rn(q[0],q[1]), __fadd_rn(q[2],q[3])),
                          __fadd_rn(__fadd_rn(q[4],q[5]), __fadd_rn(q[6],q[7])));
      v = __fadd_rn(v, __shfl_xor(v, 8, 64));
      v = __fadd_rn(v, __shfl_xor(v, 4, 64));
      v = __fadd_rn(v, __shfl_xor(v, 2, 64));
      v = __fadd_rn(v, __shfl_xor(v, 1, 64));
      blk[bb] = v;
    }
    if(li == 0) *dst = __fadd_rn(blk[0], blk[1]);
  }
}

// --------- fused: distances + argmin + softmax + quant gather ---------------
// R12 == R11 resubmitted (R11 bench died at container acquisition; source
// audited clean: uniform barriers, SGPR-legal readlane lane, no OOB).
// R11: A in VGPRs + readlane broadcast (R10's inner-loop global A loads were
// ~190us of exposed lgkmcnt stall: 2048 uniform 8B loads per thread consumed
// immediately, no TLP to cover them).
//  * prologue loads the wave's A-tile (8 rows x 256 k = 32 VGPR/lane,
//    areg[b][r] = A[r][b*64+lane], coalesced) ONCE; both chunks reuse it.
//  * inner loop: a[r][k] = readlane(areg[k>>6][r], k&63) -> SGPR operand of
//    v_fma (free); 8 readlane + 64 FMA per k, zero A memory traffic.
//    The 4-way compile-time b-unroll keeps the areg index static; lane
//    index sb*8+kk is wave-uniform runtime (legal SGPR lane operand).
//  * B path unchanged from R10: 2 full-width ds_read_b128 per 64 FMA,
//    double-buffered Bs, one barrier per stage. cur = sb&1 (nc*32+b*8 even).
//  * pipe balance per CU: VALU ~122us, LDS ~123us, overlapping.
// The per-(row,code) single-accumulator ascending-k fmaf chain is unchanged
// (readlane returns identical bits on every lane) -> distances bit-exact.
__global__ __launch_bounds__(256,2) void fused_argmin_kernel(
    const float* __restrict__ X, const float* __restrict__ CB,
    const float* __restrict__ xsq, const float* __restrict__ csq,
    float* __restrict__ hist, float* __restrict__ acc_sc,
    float* __restrict__ out)
{
  __shared__ __align__(16) float Bs[2][KC][SBW];    // 33.3 KB
  __shared__ __align__(16) float4 cstat[2][MT];     // 1 KB: {dl, kl-bits, s1, t2s}
  __shared__ int sk[MT];
  const int t  = threadIdx.x;                 // 0..255
  const int tx = t & 63;                      // code slot within wave
  const int wid = __builtin_amdgcn_readfirstlane(t >> 6);   // wave id 0..3 (uniform)
  const int m0 = blockIdx.x * MT;

  const float* Aw = X + (size_t)(m0 + wid*8)*DIMS;          // uniform base

  // ---- A-tile into registers: areg[b][r] = A[row r][k = b*64 + lane] ------
  float areg[4][8];
  #pragma unroll
  for(int b=0;b<4;b++)
    #pragma unroll
    for(int r=0;r<8;r++)
      areg[b][r] = Aw[r*DIMS + b*64 + tx];    // coalesced 256B per load

  float xs_[8];                               // wave-uniform row norms
  #pragma unroll
  for(int i=0;i<8;i++) xs_[i] = xsq[m0 + wid*8 + i];

  // ---- stage-0 prefetch + commit to buf 0 ---------------------------------
  float4 b4p[4];                              // codes t and t+256, k 0..7
  {
    const float* Bg  = CB + (size_t)t*DIMS;
    const float* Bg2 = CB + (size_t)(256 + t)*DIMS;
    b4p[0] = *(const float4*)(Bg);  b4p[1] = *(const float4*)(Bg + 4);
    b4p[2] = *(const float4*)(Bg2); b4p[3] = *(const float4*)(Bg2 + 4);
  }
  #pragma unroll
  for(int q=0;q<2;q++)
    #pragma unroll
    for(int j=0;j<4;j++){
      Bs[0][q*4+j][t]       = ((const float*)&b4p[q])[j];
      Bs[0][q*4+j][256 + t] = ((const float*)&b4p[2+q])[j];
    }
  __syncthreads();

  float acc[8][8];
  #pragma unroll
  for(int i=0;i<8;i++)
    #pragma unroll
    for(int j=0;j<8;j++) acc[i][j]=0.f;

  for(int nc=0; nc<2; nc++){
    #pragma unroll
    for(int b=0;b<4;b++){                     // compile-time: areg block index
      for(int sb=0;sb<8;sb++){                // runtime: 8 stages per k-block
        const int s_lin = nc*32 + b*8 + sb;   // global stage 0..63
        const int cur = sb & 1;               // == s_lin & 1
        // prefetch next stage into regs (latency hides under the FMA phase)
        {
          const int s2 = (s_lin+1) & 63;
          const float* Bg  = CB + (size_t)((s2>>5)*NCHUNK + t)*DIMS + (s2&31)*KC;
          const float* Bg2 = Bg + 256*DIMS;
          b4p[0] = *(const float4*)(Bg);  b4p[1] = *(const float4*)(Bg + 4);
          b4p[2] = *(const float4*)(Bg2); b4p[3] = *(const float4*)(Bg2 + 4);
        }
        // K-chain: ascending k, one fmaf chain per (row,code); A broadcast
        // from registers via readlane (no memory, no waits)
        #pragma unroll
        for(int kk=0;kk<8;kk++){
          const int lane = sb*8 + kk;         // wave-uniform
          float4 b0 = *(const float4*)&Bs[cur][kk][tx*4];        // codes 0..255
          float4 b1 = *(const float4*)&Bs[cur][kk][256 + tx*4];  // codes 256..511
          float b_[8]={b0.x,b0.y,b0.z,b0.w, b1.x,b1.y,b1.z,b1.w};
          #pragma unroll
          for(int r=0;r<8;r++){
            float av = bcast_lane(areg[b][r], lane);
            #pragma unroll
            for(int j=0;j<8;j++)
              acc[r][j] = fmaf(av, b_[j], acc[r][j]);
          }
        }
        // commit prefetched stage to the other buffer
        #pragma unroll
        for(int q=0;q<2;q++)
          #pragma unroll
          for(int j=0;j<4;j++){
            Bs[cur^1][q*4+j][t]       = ((const float*)&b4p[q])[j];
            Bs[cur^1][q*4+j][256 + t] = ((const float*)&b4p[2+q])[j];
          }
        __syncthreads();
      }
    }

    // ---- chunk epilogue ----------------------------------------------------
    {
      const int n0c = nc * NCHUNK;
      float csv[8];
      { float4 c0 = *(const float4*)(csq + n0c + tx*4);
        float4 c1 = *(const float4*)(csq + n0c + 256 + tx*4);
        csv[0]=c0.x; csv[1]=c0.y; csv[2]=c0.z; csv[3]=c0.w;
        csv[4]=c1.x; csv[5]=c1.y; csv[6]=c1.z; csv[7]=c1.w; }
      #pragma unroll
      for(int i=0;i<8;i++){
        float xs = xs_[i];
        float d[8];
        #pragma unroll
        for(int j=0;j<8;j++){
          // contraction-safe: 2*acc exact, fl(t - 2*acc)
          float d2 = (xs + csv[j]) - 2.0f*acc[i][j];
          d[j] = sqrtf(fmaxf(d2, 0.f));
        }
        // thread-local argmin, ascending kidx, strict < (first-occurrence tie)
        float dl = INFINITY; int kl = 0;
        #pragma unroll
        for(int j=0;j<8;j++){
          int kidx = n0c + (j>>2)*256 + tx*4 + (j&3);   // ascending in j
          if(d[j] < dl){ dl = d[j]; kl = kidx; }
        }
        // full-wave butterfly (64 lanes share this row)
        #pragma unroll
        for(int off=1; off<64; off<<=1){
          float od = __shfl_xor(dl, off, 64);
          int   ok = __shfl_xor(kl, off, 64);
          if(od < dl || (od == dl && ok < kl)){ dl = od; kl = ok; }
        }
        // chunk softmax stats shifted at chunk min: l = (dl - d)*100 <= 0
        float s1=0.f, t2s=0.f;
        #pragma unroll
        for(int j=0;j<8;j++){
          float l = (dl - d[j])*100.0f;
          float e = expf(l);
          s1 += e; t2s = fmaf(e, l, t2s);
        }
        #pragma unroll
        for(int off=1; off<64; off<<=1){
          s1  += __shfl_xor(s1,  off, 64);
          t2s += __shfl_xor(t2s, off, 64);
        }
        if(tx == 0)
          cstat[nc][wid*8 + i] = make_float4(dl, __int_as_float(kl), s1, t2s);
      }
      #pragma unroll
      for(int i=0;i<8;i++)
        #pragma unroll
        for(int j=0;j<8;j++) acc[i][j]=0.f;
    }
  }

  // ---- final merge: one row per lane of wave 0 (ascending nc = same
  //      first-occurrence semantics as the sequential merge) ----------------
  __syncthreads();
  float plogp = 0.f;
  if(t < MT){
    float4 c0 = cstat[0][t];
    float dm = c0.x; int km = __float_as_int(c0.y);
    float Ss = c0.z; float Ts = c0.w;
    {
      float4 cn = cstat[1][t];
      float dl = cn.x; int kl = __float_as_int(cn.y);
      float s1 = cn.z, t2s = cn.w;
      if(dl < dm){                       // strict <: tie keeps chunk 0 (smaller idx)
        float del = 100.0f*(dl - dm); float al = expf(del);
        Ts = al*(Ts + Ss*del) + t2s;
        Ss = al*Ss + s1;
        dm = dl; km = kl;
      } else {
        float del = 100.0f*(dm - dl); float al = expf(del);
        Ts += al*(t2s + s1*del);
        Ss += al*s1;
      }
    }
    int n = m0 + t;
    out[IDX_OFF + n] = (float)km;
    sk[t] = km;
    atomicAdd(hist + km, 1.0f);
    plogp = Ts/Ss - logf(Ss);
  }
  plogp = wsum64(plogp);
  if((t & 63) == 0) atomicAdd(acc_sc + 1, plogp);   // waves 1-3 add 0

  // ---- fused quant gather + mse -------------------------------------------
  __syncthreads();                 // sk[] visible to all waves
  {
    int lane = t & 63;             // 4 waves x 8 rows
    int row0 = wid*8;
    float mse = 0.f;
    #pragma unroll
    for(int r=0;r<8;r++){
      int n = m0 + row0 + r;
      int k = sk[row0 + r];
      float4 cb4 = *(const float4*)(CB + (size_t)k*DIMS + lane*4);
      float4 x4  = *(const float4*)(X  + (size_t)n*DIMS + lane*4);
      float e0=x4.x-cb4.x, e1=x4.y-cb4.y, e2=x4.z-cb4.z, e3=x4.w-cb4.w;
      mse += e0*e0 + e1*e1 + e2*e2 + e3*e3;
      *reinterpret_cast<float4*>(out + (size_t)n*DIMS + lane*4) = cb4;
    }
    mse = wsum64(mse);
    if(lane==0) atomicAdd(acc_sc+0, mse);
  }
}

// ---------------- finalize scalars (float32) --------------------------------
__global__ __launch_bounds__(256) void finalize_kernel(const float* __restrict__ hist,
                                                       const float* __restrict__ acc_sc,
                                                       float* __restrict__ out){
  __shared__ float red[256];
  int t = threadIdx.x;
  float s = 0.f;
  #pragma unroll
  for(int c=0;c<4;c++){
    float ap = hist[c*256 + t] * (1.0f/32768.0f);   // avg_probs ~ argmin histogram
    s += ap * logf(ap + 1e-5f);
  }
  red[t] = s; __syncthreads();
  for(int off=128; off; off>>=1){
    if(t<off) red[t]+=red[t+off];
    __syncthreads();
  }
  if(t==0){
    float avg_entropy    = -red[0];
    float mse            = acc_sc[0] * (1.0f/8388608.0f);
    float sample_entropy = -(acc_sc[1] * (1.0f/32768.0f));
    float commit = 0.5f*mse*0.25f;
    float cbl    = 0.5f*mse;
    float ent    = (sample_entropy - avg_entropy)*0.1f;
    float vq     = cbl + commit + ent;
    out[SC_OFF+0] = vq;
    out[SC_OFF+1] = commit;
    out[SC_OFF+2] = cbl;
    out[SC_OFF+3] = ent;
  }
}

extern "C" void kernel_launch(void* const* d_in, const int* in_sizes, int n_in,
                              void* d_out, int out_size, void* d_ws, size_t ws_size,
                              hipStream_t stream){
  const float* X  = (const float*)d_in[0];
  const float* CB = (const float*)d_in[1];
  float* out = (float*)d_out;                        // float32 output buffer
  float* xsq     = (float*)d_ws;                     // [32768]
  float* csq     = xsq + N_ROWS;                     // [1024]
  float* hist    = csq + K_CODES;                    // [1024]
  float* acc_sc  = hist + K_CODES;                   // [2]: mse, plogp

  hipMemsetAsync(hist, 0, (K_CODES+2)*sizeof(float), stream);
  rowsq_np512_kernel <<<(K_CODES+N_ROWS)/64, 256, 0, stream>>>(X, CB, xsq, csq);
  fused_argmin_kernel<<<N_ROWS/MT, 256, 0, stream>>>(X, CB, xsq, csq, hist, acc_sc, out);
  finalize_kernel    <<<1, 256, 0, stream>>>(hist, acc_sc, out);
}